// Round 3
// baseline (50.978 us; speedup 1.0000x reference)
//
#include <hip/hip_runtime.h>

#define NPTS 512
#define DIM  128
#define EPSF 1e-16f
#define SROW 132   // padded LDS row stride (floats); 132 -> each 8-lane octet's
                   // 16B windows tile all 32 banks (optimal for ds_read_b128)

// ---------------------------------------------------------------------------
// Kernel 1: full distance matrix D[512][512] via tiled X·X^T.
// Grid: 256 blocks (16x16 tiles of 32x32), 512 threads, 2 outputs/thread.
// Reference semantics: draw = relu(ni + nj - 2*dot);
//                      d = (draw==0) ? EPS : sqrt(draw+EPS)+EPS.
// Also resets the finalize counter for kernel 2 (runs before it on stream).
// ---------------------------------------------------------------------------
__global__ __launch_bounds__(512) void distmat(
    const float* __restrict__ X,
    float* __restrict__ D,
    unsigned* __restrict__ counter)
{
    __shared__ float A[32 * SROW];
    __shared__ float B[32 * SROW];
    __shared__ float nA[32], nB[32];

    if (blockIdx.x == 0 && threadIdx.x == 0) *counter = 0u;

    const int bi = blockIdx.x & 15;
    const int bj = blockIdx.x >> 4;
    const int r0 = bi * 32, c0 = bj * 32;
    const int t = threadIdx.x;

    // coalesced stage: 2 tiles x 1024 float4; 2 per thread per tile
    for (int g = t; g < 1024; g += 512) {
        const int r = g >> 5, c4 = g & 31;
        *reinterpret_cast<float4*>(&A[r * SROW + c4 * 4]) =
            reinterpret_cast<const float4*>(X + (size_t)(r0 + r) * DIM)[c4];
        *reinterpret_cast<float4*>(&B[r * SROW + c4 * 4]) =
            reinterpret_cast<const float4*>(X + (size_t)(c0 + r) * DIM)[c4];
    }
    __syncthreads();

    // row norms (32 threads per tile, conflict-free: bank = 4*row mod 32 octets)
    if (t < 64) {
        const float* src = (t < 32) ? &A[t * SROW] : &B[(t - 32) * SROW];
        float s = 0.f;
        for (int c4 = 0; c4 < 32; ++c4) {
            float4 v = *reinterpret_cast<const float4*>(src + c4 * 4);
            s += v.x * v.x + v.y * v.y + v.z * v.z + v.w * v.w;
        }
        if (t < 32) nA[t] = s; else nB[t - 32] = s;
    }
    __syncthreads();

    const int c  = t & 31;   // output col in tile
    const int ty = t >> 5;   // 0..15 ; rows ty, ty+16
    float acc[2] = {0.f, 0.f};
    for (int k4 = 0; k4 < 32; ++k4) {
        const float4 bv = *reinterpret_cast<const float4*>(&B[c * SROW + k4 * 4]);
#pragma unroll
        for (int q = 0; q < 2; ++q) {
            const float4 av = *reinterpret_cast<const float4*>(&A[(ty + 16 * q) * SROW + k4 * 4]);
            acc[q] += av.x * bv.x + av.y * bv.y + av.z * bv.z + av.w * bv.w;
        }
    }
#pragma unroll
    for (int q = 0; q < 2; ++q) {
        const int r = ty + 16 * q;
        const float draw = fmaxf(nA[r] + nB[c] - 2.f * acc[q], 0.f);
        D[(size_t)(r0 + r) * NPTS + (c0 + c)] =
            (draw == 0.f) ? EPSF : (sqrtf(draw + EPSF) + EPSF);
    }
}

// ---------------------------------------------------------------------------
// Kernel 2: triplet accumulation + fused last-block finalize.
// Grid: 256 blocks x 512 threads; block b handles anchors 2b, 2b+1;
// thread t owns negative candidate k = t.
// ---------------------------------------------------------------------------
__global__ __launch_bounds__(512) void triplet_sum(
    const float* __restrict__ D,
    const int* __restrict__ labels,
    const float* __restrict__ bias,
    float* __restrict__ psum,
    unsigned* __restrict__ pcnt,
    unsigned* __restrict__ counter,
    float* __restrict__ out)
{
    __shared__ int      lab[NPTS];
    __shared__ float    drow[2][NPTS];     // rows i0, i0+1 (contiguous in D)
    __shared__ int      poslist[2][96];
    __shared__ int      npos[2];
    __shared__ float    wsum[8];
    __shared__ unsigned wcnt[8];
    __shared__ float    fs[256];
    __shared__ unsigned fc[256];
    __shared__ int      lastFlag;

    const int blk = blockIdx.x;
    const int t   = threadIdx.x;
    const int i0  = blk * 2;

    lab[t] = labels[t];
    if (t < 256) {   // 4 KB contiguous: D rows i0 and i0+1
        reinterpret_cast<float4*>(&drow[0][0])[t] =
            reinterpret_cast<const float4*>(D + (size_t)i0 * NPTS)[t];
    }
    if (t < 2) npos[t] = 0;
    __syncthreads();

    const int li0 = lab[i0], li1 = lab[i0 + 1];
    {
        const int j = t;
        if (lab[j] == li0 && j != i0)     { int q = atomicAdd(&npos[0], 1); poslist[0][q] = j; }
        if (lab[j] == li1 && j != i0 + 1) { int q = atomicAdd(&npos[1], 1); poslist[1][q] = j; }
    }
    __syncthreads();
    if (t < 2) {   // deterministic order: insertion sort (~8 entries)
        const int n = npos[t];
        for (int a2 = 1; a2 < n; ++a2) {
            int v = poslist[t][a2];
            int b2 = a2 - 1;
            while (b2 >= 0 && poslist[t][b2] > v) { poslist[t][b2 + 1] = poslist[t][b2]; --b2; }
            poslist[t][b2 + 1] = v;
        }
    }
    __syncthreads();

    const float bv = bias[0];
    float    lsum = 0.f;
    unsigned lcnt = 0u;
#pragma unroll
    for (int a = 0; a < 2; ++a) {
        const int   la = lab[i0 + a];
        const float* dr = &drow[a][0];
        if (lab[t] != la) {              // t is the negative k (k==anchor excluded)
            const float dik = dr[t];
            const int n = npos[a];
            for (int q = 0; q < n; ++q) {
                const float s = dr[poslist[a][q]] - dik + bv;   // poslist read = broadcast
                if (s > 0.f) { lsum += s; lcnt += (s > EPSF) ? 1u : 0u; }
            }
        }
    }

    // wave (64) shuffle reduce, then cross-wave
#pragma unroll
    for (int off = 32; off > 0; off >>= 1) {
        lsum += __shfl_down(lsum, off);
        lcnt += __shfl_down(lcnt, off);
    }
    if ((t & 63) == 0) { wsum[t >> 6] = lsum; wcnt[t >> 6] = lcnt; }
    __syncthreads();
    if (t == 0) {
        float s = 0.f; unsigned c = 0u;
#pragma unroll
        for (int w = 0; w < 8; ++w) { s += wsum[w]; c += wcnt[w]; }
        psum[blk] = s;
        pcnt[blk] = c;
    }

    // -------- fused finalize: last block reduces all 256 partials ----------
    __threadfence();                     // release partials (device scope)
    if (t == 0) {
        const unsigned old = atomicAdd(counter, 1u);
        lastFlag = (old == gridDim.x - 1) ? 1 : 0;
    }
    __syncthreads();
    if (lastFlag) {
        __threadfence();                 // acquire
        if (t < 256) {
            volatile const float*    vp = psum;
            volatile const unsigned* vc = pcnt;
            fs[t] = vp[t];
            fc[t] = vc[t];
        }
        __syncthreads();
        for (int off = 128; off > 0; off >>= 1) {
            if (t < off) { fs[t] += fs[t + off]; fc[t] += fc[t + off]; }
            __syncthreads();
        }
        if (t == 0) out[0] = fs[0] / ((float)fc[0] + 1e-16f);
    }
}

extern "C" void kernel_launch(void* const* d_in, const int* in_sizes, int n_in,
                              void* d_out, int out_size, void* d_ws, size_t ws_size,
                              hipStream_t stream) {
    const float* X      = (const float*)d_in[0];
    const int*   labels = (const int*)d_in[1];
    const float* bias   = (const float*)d_in[2];
    float*       out    = (float*)d_out;

    float*    D       = (float*)d_ws;                                   // 1 MB
    float*    psum    = (float*)((char*)d_ws + NPTS * NPTS * 4);        // 1 KB
    unsigned* pcnt    = (unsigned*)((char*)psum + 256 * 4);             // 1 KB
    unsigned* counter = (unsigned*)((char*)pcnt + 256 * 4);             // 4 B

    distmat<<<256, 512, 0, stream>>>(X, D, counter);
    triplet_sum<<<256, 512, 0, stream>>>(D, labels, bias, psum, pcnt, counter, out);
}

// Round 4
// 21.755 us; speedup vs baseline: 2.3433x; 2.3433x over previous
//
#include <hip/hip_runtime.h>

#define NPTS 512
#define DIM  128
#define EPSF 1e-16f
#define SROW 132   // padded LDS row stride (floats); 132 -> each 8-lane octet's
                   // 16B windows tile all 32 banks (optimal for ds_read_b128)

// ---------------------------------------------------------------------------
// Kernel 1: full distance matrix D[512][512] via tiled X·X^T.
// Grid: 256 blocks (16x16 tiles of 32x32), 512 threads, 2 outputs/thread.
// Reference semantics: draw = relu(ni + nj - 2*dot);
//                      d = (draw==0) ? EPS : sqrt(draw+EPS)+EPS.
// ---------------------------------------------------------------------------
__global__ __launch_bounds__(512) void distmat(
    const float* __restrict__ X,
    float* __restrict__ D)
{
    __shared__ float A[32 * SROW];
    __shared__ float B[32 * SROW];
    __shared__ float nA[32], nB[32];

    const int bi = blockIdx.x & 15;
    const int bj = blockIdx.x >> 4;
    const int r0 = bi * 32, c0 = bj * 32;
    const int t = threadIdx.x;

    // coalesced stage: 2 tiles x 1024 float4; 2 per thread per tile
    for (int g = t; g < 1024; g += 512) {
        const int r = g >> 5, c4 = g & 31;
        *reinterpret_cast<float4*>(&A[r * SROW + c4 * 4]) =
            reinterpret_cast<const float4*>(X + (size_t)(r0 + r) * DIM)[c4];
        *reinterpret_cast<float4*>(&B[r * SROW + c4 * 4]) =
            reinterpret_cast<const float4*>(X + (size_t)(c0 + r) * DIM)[c4];
    }
    __syncthreads();

    // row norms (32 threads per tile, conflict-free: octet pattern from SROW pad)
    if (t < 64) {
        const float* src = (t < 32) ? &A[t * SROW] : &B[(t - 32) * SROW];
        float s = 0.f;
        for (int c4 = 0; c4 < 32; ++c4) {
            float4 v = *reinterpret_cast<const float4*>(src + c4 * 4);
            s += v.x * v.x + v.y * v.y + v.z * v.z + v.w * v.w;
        }
        if (t < 32) nA[t] = s; else nB[t - 32] = s;
    }
    __syncthreads();

    const int c  = t & 31;   // output col in tile
    const int ty = t >> 5;   // 0..15 ; rows ty, ty+16
    float acc[2] = {0.f, 0.f};
    for (int k4 = 0; k4 < 32; ++k4) {
        const float4 bv = *reinterpret_cast<const float4*>(&B[c * SROW + k4 * 4]);
#pragma unroll
        for (int q = 0; q < 2; ++q) {
            const float4 av = *reinterpret_cast<const float4*>(&A[(ty + 16 * q) * SROW + k4 * 4]);
            acc[q] += av.x * bv.x + av.y * bv.y + av.z * bv.z + av.w * bv.w;
        }
    }
#pragma unroll
    for (int q = 0; q < 2; ++q) {
        const int r = ty + 16 * q;
        const float draw = fmaxf(nA[r] + nB[c] - 2.f * acc[q], 0.f);
        D[(size_t)(r0 + r) * NPTS + (c0 + c)] =
            (draw == 0.f) ? EPSF : (sqrtf(draw + EPSF) + EPSF);
    }
}

// ---------------------------------------------------------------------------
// Kernel 2: triplet accumulation -> per-block partials (no fences, no fusion).
// Grid: 256 blocks x 512 threads; block b handles anchors 2b, 2b+1;
// thread t owns negative candidate k = t.
// ---------------------------------------------------------------------------
__global__ __launch_bounds__(512) void triplet_sum(
    const float* __restrict__ D,
    const int* __restrict__ labels,
    const float* __restrict__ bias,
    float* __restrict__ psum,
    unsigned* __restrict__ pcnt)
{
    __shared__ int      lab[NPTS];
    __shared__ float    drow[2][NPTS];     // rows i0, i0+1 (contiguous in D)
    __shared__ int      poslist[2][96];
    __shared__ int      npos[2];
    __shared__ float    wsum[8];
    __shared__ unsigned wcnt[8];

    const int blk = blockIdx.x;
    const int t   = threadIdx.x;
    const int i0  = blk * 2;

    lab[t] = labels[t];
    if (t < 256) {   // 4 KB contiguous: D rows i0 and i0+1
        reinterpret_cast<float4*>(&drow[0][0])[t] =
            reinterpret_cast<const float4*>(D + (size_t)i0 * NPTS)[t];
    }
    if (t < 2) npos[t] = 0;
    __syncthreads();

    const int li0 = lab[i0], li1 = lab[i0 + 1];
    {
        const int j = t;
        if (lab[j] == li0 && j != i0)     { int q = atomicAdd(&npos[0], 1); poslist[0][q] = j; }
        if (lab[j] == li1 && j != i0 + 1) { int q = atomicAdd(&npos[1], 1); poslist[1][q] = j; }
    }
    __syncthreads();
    if (t < 2) {   // deterministic order: insertion sort (~8 entries)
        const int n = npos[t];
        for (int a2 = 1; a2 < n; ++a2) {
            int v = poslist[t][a2];
            int b2 = a2 - 1;
            while (b2 >= 0 && poslist[t][b2] > v) { poslist[t][b2 + 1] = poslist[t][b2]; --b2; }
            poslist[t][b2 + 1] = v;
        }
    }
    __syncthreads();

    const float bv = bias[0];
    float    lsum = 0.f;
    unsigned lcnt = 0u;
#pragma unroll
    for (int a = 0; a < 2; ++a) {
        const int   la = lab[i0 + a];
        const float* dr = &drow[a][0];
        if (lab[t] != la) {              // t is the negative k (k==anchor excluded)
            const float dik = dr[t];
            const int n = npos[a];
            for (int q = 0; q < n; ++q) {
                const float s = dr[poslist[a][q]] - dik + bv;   // poslist read = broadcast
                if (s > 0.f) { lsum += s; lcnt += (s > EPSF) ? 1u : 0u; }
            }
        }
    }

    // wave (64) shuffle reduce, then cross-wave
#pragma unroll
    for (int off = 32; off > 0; off >>= 1) {
        lsum += __shfl_down(lsum, off);
        lcnt += __shfl_down(lcnt, off);
    }
    if ((t & 63) == 0) { wsum[t >> 6] = lsum; wcnt[t >> 6] = lcnt; }
    __syncthreads();
    if (t == 0) {
        float s = 0.f; unsigned c = 0u;
#pragma unroll
        for (int w = 0; w < 8; ++w) { s += wsum[w]; c += wcnt[w]; }
        psum[blk] = s;
        pcnt[blk] = c;
    }
}

// ---------------------------------------------------------------------------
// Kernel 3: deterministic tree reduction of 256 partials + final divide.
// ---------------------------------------------------------------------------
__global__ __launch_bounds__(256) void triplet_finalize(
    const float* __restrict__ psum,
    const unsigned* __restrict__ pcnt,
    float* __restrict__ out)
{
    __shared__ float    ss[256];
    __shared__ unsigned sc[256];
    const int t = threadIdx.x;
    ss[t] = psum[t];
    sc[t] = pcnt[t];
    __syncthreads();
    for (int off = 128; off > 0; off >>= 1) {
        if (t < off) { ss[t] += ss[t + off]; sc[t] += sc[t + off]; }
        __syncthreads();
    }
    if (t == 0) out[0] = ss[0] / ((float)sc[0] + 1e-16f);
}

extern "C" void kernel_launch(void* const* d_in, const int* in_sizes, int n_in,
                              void* d_out, int out_size, void* d_ws, size_t ws_size,
                              hipStream_t stream) {
    const float* X      = (const float*)d_in[0];
    const int*   labels = (const int*)d_in[1];
    const float* bias   = (const float*)d_in[2];
    float*       out    = (float*)d_out;

    float*    D    = (float*)d_ws;                                // 1 MB
    float*    psum = (float*)((char*)d_ws + NPTS * NPTS * 4);     // 1 KB
    unsigned* pcnt = (unsigned*)((char*)psum + 256 * 4);          // 1 KB

    distmat<<<256, 512, 0, stream>>>(X, D);
    triplet_sum<<<256, 512, 0, stream>>>(D, labels, bias, psum, pcnt);
    triplet_finalize<<<1, 256, 0, stream>>>(psum, pcnt, out);
}

// Round 5
// 20.379 us; speedup vs baseline: 2.5014x; 1.0675x over previous
//
#include <hip/hip_runtime.h>

#define NPTS 512
#define DIM  128
#define EPSF 1e-16f

// ---------------------------------------------------------------------------
// Fused kernel: distance rows + triplet accumulation, no D materialization.
// Grid: 256 blocks x 512 threads; block b handles anchors i0=2b, 2b+1.
// Dot: 4 lanes per j (32 dims each via interleaved float4 cols) + shfl_xor
//      butterfly; the j-row is read once and dotted against BOTH anchors.
// Reference semantics: draw = relu(ni + nj - 2*dot);
//                      d = (draw==0) ? EPS : sqrt(draw+EPS)+EPS.
// ---------------------------------------------------------------------------
__global__ __launch_bounds__(512) void triplet_fused(
    const float* __restrict__ X,
    const int* __restrict__ labels,
    const float* __restrict__ bias,
    float* __restrict__ psum,
    unsigned* __restrict__ pcnt)
{
    __shared__ int      lab[NPTS];
    __shared__ float    drow[2][NPTS];
    __shared__ float4   xi4[2][DIM / 4];
    __shared__ int      poslist[2][96];
    __shared__ int      npos[2];
    __shared__ float    wsum[8];
    __shared__ unsigned wcnt[8];

    const int blk = blockIdx.x;
    const int t   = threadIdx.x;
    const int i0  = blk * 2;

    lab[t] = labels[t];
    if (t < 64) {               // stage the two anchor rows (32 float4 each)
        const int a = t >> 5, c4 = t & 31;
        xi4[a][c4] = reinterpret_cast<const float4*>(X + (size_t)(i0 + a) * DIM)[c4];
    }
    if (t < 2) npos[t] = 0;
    __syncthreads();

    const int jl = t >> 2;      // 0..127 : j within a 128-row quarter
    const int ch = t & 3;       // dim chunk (32 dims, interleaved float4 cols)

    // anchor fragments in registers
    float4 w0[8], w1[8];
#pragma unroll
    for (int m = 0; m < 8; ++m) { w0[m] = xi4[0][ch + 4 * m]; w1[m] = xi4[1][ch + 4 * m]; }

    // anchor norms via the same 4-lane butterfly
    float n0 = 0.f, n1 = 0.f;
#pragma unroll
    for (int m = 0; m < 8; ++m) {
        float4 a = w0[m], b = w1[m];
        n0 += a.x * a.x + a.y * a.y + a.z * a.z + a.w * a.w;
        n1 += b.x * b.x + b.y * b.y + b.z * b.z + b.w * b.w;
    }
    n0 += __shfl_xor(n0, 1); n0 += __shfl_xor(n0, 2);
    n1 += __shfl_xor(n1, 1); n1 += __shfl_xor(n1, 2);

    // distance rows: 4 quarters of 128 j's; row j read once, dotted vs both anchors
#pragma unroll
    for (int q = 0; q < 4; ++q) {
        const int j = q * 128 + jl;
        const float4* xj = reinterpret_cast<const float4*>(X + (size_t)j * DIM);
        float d0 = 0.f, d1 = 0.f, nj = 0.f;
#pragma unroll
        for (int m = 0; m < 8; ++m) {
            const float4 v = xj[ch + 4 * m];
            const float4 a = w0[m], b = w1[m];
            d0 += v.x * a.x + v.y * a.y + v.z * a.z + v.w * a.w;
            d1 += v.x * b.x + v.y * b.y + v.z * b.z + v.w * b.w;
            nj += v.x * v.x + v.y * v.y + v.z * v.z + v.w * v.w;
        }
        d0 += __shfl_xor(d0, 1); d0 += __shfl_xor(d0, 2);
        d1 += __shfl_xor(d1, 1); d1 += __shfl_xor(d1, 2);
        nj += __shfl_xor(nj, 1); nj += __shfl_xor(nj, 2);
        if (ch == 0) {
            const float r0 = fmaxf(n0 + nj - 2.f * d0, 0.f);
            const float r1 = fmaxf(n1 + nj - 2.f * d1, 0.f);
            drow[0][j] = (r0 == 0.f) ? EPSF : (sqrtf(r0 + EPSF) + EPSF);
            drow[1][j] = (r1 == 0.f) ? EPSF : (sqrtf(r1 + EPSF) + EPSF);
        }
    }
    __syncthreads();

    // positive lists (same label, j != anchor), then deterministic sort
    const int li0 = lab[i0], li1 = lab[i0 + 1];
    {
        const int j = t;
        if (lab[j] == li0 && j != i0)     { int q = atomicAdd(&npos[0], 1); poslist[0][q] = j; }
        if (lab[j] == li1 && j != i0 + 1) { int q = atomicAdd(&npos[1], 1); poslist[1][q] = j; }
    }
    __syncthreads();
    if (t < 2) {                // insertion sort (~8 entries)
        const int n = npos[t];
        for (int a2 = 1; a2 < n; ++a2) {
            int v = poslist[t][a2];
            int b2 = a2 - 1;
            while (b2 >= 0 && poslist[t][b2] > v) { poslist[t][b2 + 1] = poslist[t][b2]; --b2; }
            poslist[t][b2 + 1] = v;
        }
    }
    __syncthreads();

    // triplet accumulation: thread t owns negative candidate k = t
    const float bv = bias[0];
    float    lsum = 0.f;
    unsigned lcnt = 0u;
#pragma unroll
    for (int a = 0; a < 2; ++a) {
        const int    la = lab[i0 + a];
        const float* dr = &drow[a][0];
        if (lab[t] != la) {
            const float dik = dr[t];
            const int n = npos[a];
            for (int q = 0; q < n; ++q) {
                const float s = dr[poslist[a][q]] - dik + bv;   // poslist read = broadcast
                if (s > 0.f) { lsum += s; lcnt += (s > EPSF) ? 1u : 0u; }
            }
        }
    }

    // wave (64) shuffle reduce, then cross-wave
#pragma unroll
    for (int off = 32; off > 0; off >>= 1) {
        lsum += __shfl_down(lsum, off);
        lcnt += __shfl_down(lcnt, off);
    }
    if ((t & 63) == 0) { wsum[t >> 6] = lsum; wcnt[t >> 6] = lcnt; }
    __syncthreads();
    if (t == 0) {
        float s = 0.f; unsigned c = 0u;
#pragma unroll
        for (int w = 0; w < 8; ++w) { s += wsum[w]; c += wcnt[w]; }
        psum[blk] = s;
        pcnt[blk] = c;
    }
}

// ---------------------------------------------------------------------------
// Finalize: single 64-lane wave, fixed-order serial+shuffle reduce (determin.)
// ---------------------------------------------------------------------------
__global__ __launch_bounds__(64) void triplet_finalize(
    const float* __restrict__ psum,
    const unsigned* __restrict__ pcnt,
    float* __restrict__ out)
{
    const int t = threadIdx.x;
    float    s = psum[t] + psum[t + 64] + psum[t + 128] + psum[t + 192];
    unsigned c = pcnt[t] + pcnt[t + 64] + pcnt[t + 128] + pcnt[t + 192];
#pragma unroll
    for (int off = 32; off > 0; off >>= 1) {
        s += __shfl_down(s, off);
        c += __shfl_down(c, off);
    }
    if (t == 0) out[0] = s / ((float)c + 1e-16f);
}

extern "C" void kernel_launch(void* const* d_in, const int* in_sizes, int n_in,
                              void* d_out, int out_size, void* d_ws, size_t ws_size,
                              hipStream_t stream) {
    const float* X      = (const float*)d_in[0];
    const int*   labels = (const int*)d_in[1];
    const float* bias   = (const float*)d_in[2];
    float*       out    = (float*)d_out;

    float*    psum = (float*)d_ws;                        // 256 floats
    unsigned* pcnt = (unsigned*)((char*)d_ws + 256 * 4);  // 256 uints

    triplet_fused<<<256, 512, 0, stream>>>(X, labels, bias, psum, pcnt);
    triplet_finalize<<<1, 64, 0, stream>>>(psum, pcnt, out);
}